// Round 5
// baseline (190.077 us; speedup 1.0000x reference)
//
#include <hip/hip_runtime.h>
#include <hip/hip_bf16.h>

// Locally-connected conv, ALL FP32 in/out, bf16 MFMA compute.
//   x:   (32, 16, 64, 64)        float
//   w:   (60, 60, 16, 5, 5, 16)  float   (per-position 400x16, k innermost)
//   out: (32, 16, 60, 60)        float
//
// Round-5 structure (fixes round-4 latency starvation at 1.57 TB/s):
//  * W staged with 7 independent coalesced float4/thread -> sWraw[m][k]
//    (raw fp32, stride 20 => aligned b128 LDS writes); transpose+cvt happens
//    on the LDS *read* side (8x ds_read_b32 per B-frag, ~conflict-free).
//  * Reduction index reordered to k_r=(uv, c) with c innermost: A-fragment
//    = 8 channel-consecutive bf16 = one aligned 16B global load from
//    prepassed xc[b][h][w][c] (4.2 MB, L2-resident, XCD-swizzled locality).
//    No X LDS, no gathers.
//  * LDS 40.7 KB -> 4 blocks/CU; launch_bounds(256,4).

#define OUT_HW 60
#define IN_HW  64
#define CIN    16
#define COUT   16
#define NPOS   3600              // OUT_HW*OUT_HW
#define BK     512               // NB*COUT
#define XC_ELE (32u * 64u * 64u * 16u)   // 2,097,152 bf16 elements

typedef __attribute__((ext_vector_type(8))) short bf16x8;
typedef __attribute__((ext_vector_type(4))) float f32x4;

static __device__ __forceinline__ unsigned pk2(float a, float b) {
    union { __hip_bfloat162 h; unsigned u; } cv;
    cv.h = __float22bfloat162_rn(make_float2(a, b));
    return cv.u;
}

// ---- prepass: xc[b][h][w][c] bf16 <- x[b][c][h][w] fp32 ----
__global__ __launch_bounds__(256)
void make_xc(const float* __restrict__ x, ushort* __restrict__ xc) {
    const int bh = blockIdx.x;               // b*64 + h
    const int b = bh >> 6, h = bh & 63;
    const int t = threadIdx.x;
    const int cq = t & 3, wc = t >> 2;       // wc 0..63, cq 0..3 (c = cq*4+e)
    const float* src = x + ((size_t)(b * CIN) * IN_HW + h) * IN_HW + wc;
    float f[4];
#pragma unroll
    for (int e = 0; e < 4; ++e)
        f[e] = src[(size_t)(cq * 4 + e) * (IN_HW * IN_HW)];
    union { ushort4 v; unsigned u[2]; } o;
    o.u[0] = pk2(f[0], f[1]);
    o.u[1] = pk2(f[2], f[3]);
    // write: wave covers contiguous 512B
    *(ushort4*)&xc[((size_t)bh * IN_HW + wc) * CIN + cq * 4] = o.v;
}

// ---- main: one block (256 thr, 4 K-split waves) per output position ----
template<int PACKED>
__global__ __launch_bounds__(256, 4)
void lc_pos(const ushort* __restrict__ xc, const float* __restrict__ w,
            float* __restrict__ dst) {
    __shared__ float sWraw[400 * 20];        // 32,000 B  [m][k], stride 20
    __shared__ float sRed[4][32 * 17];       //  8,704 B

    const int bid = blockIdx.x;
    const int pos = (bid & 7) * 450 + (bid >> 3);   // XCD swizzle (bijective)
    const int i = pos / OUT_HW, j = pos - i * OUT_HW;
    const int t = threadIdx.x;

    // ---- stage W: 7 independent coalesced float4 per thread ----
    {
        const float4* wf4 = (const float4*)(w + (size_t)pos * 6400);
        float4 vv[7];
#pragma unroll
        for (int it = 0; it < 7; ++it) {
            const int f = t + (it << 8);
            if (f < 1600) vv[it] = wf4[f];
        }
#pragma unroll
        for (int it = 0; it < 7; ++it) {
            const int f = t + (it << 8);
            if (f < 1600) {
                const int m = f >> 2, k4 = (f & 3) << 2;   // 20m+k4 ≡ 0 mod 4 -> b128 ok
                *(float4*)&sWraw[m * 20 + k4] = vv[it];
            }
        }
    }
    __syncthreads();

    // ---- compute: k_r=(uv,c) ordering; wave wv does chunks {wv, wv+4, ...} ----
    const int lane = t & 63, wv = t >> 6;
    const int l15 = lane & 15, q = lane >> 4;
    const int qh = q >> 1, c0 = (q & 1) << 3;
    f32x4 acc0 = {0.f, 0.f, 0.f, 0.f}, acc1 = {0.f, 0.f, 0.f, 0.f};
    const int base_hw = i * IN_HW + j;

    for (int cc = wv; cc < 13; cc += 4) {
        const int uvB = cc * 2 + qh;
        const int okB = (uvB < 25);
        float bfv[8];
#pragma unroll
        for (int jj = 0; jj < 8; ++jj) {
            const int c = c0 + jj;
            bfv[jj] = okB ? sWraw[(c * 25 + uvB) * 20 + l15] : 0.f;
        }
        union { bf16x8 v; unsigned u[4]; } pb;
#pragma unroll
        for (int jj = 0; jj < 4; ++jj) pb.u[jj] = pk2(bfv[2 * jj], bfv[2 * jj + 1]);

        const int uvA = okB ? uvB : 24;             // W=0 there; any finite x ok
        const int uA = (uvA * 13) >> 6;             // uv/5 for uv<=24
        const int vA = uvA - 5 * uA;
        const size_t xoff = (size_t)l15 * (IN_HW * IN_HW * CIN)
                          + (size_t)(base_hw + uA * IN_HW + vA) * CIN + c0;
        const bf16x8 a0 = *(const bf16x8*)(xc + xoff);                    // b = l15
        const bf16x8 a1 = *(const bf16x8*)(xc + xoff + 16u * IN_HW * IN_HW * CIN); // b+16
        acc0 = __builtin_amdgcn_mfma_f32_16x16x32_bf16(a0, pb.v, acc0, 0, 0, 0);
        acc1 = __builtin_amdgcn_mfma_f32_16x16x32_bf16(a1, pb.v, acc1, 0, 0, 0);
    }

    // ---- K-split reduce (proven round-4 pattern) ----
#pragma unroll
    for (int r = 0; r < 4; ++r) {
        sRed[wv][(q * 4 + r) * 17 + l15]      = acc0[r];   // D rows b = q*4+r
        sRed[wv][(q * 4 + r + 16) * 17 + l15] = acc1[r];   // b + 16
    }
    __syncthreads();
#pragma unroll
    for (int h = 0; h < 2; ++h) {
        const int o = t + h * 256;                  // o = b*16 + k
        const int idx = (o >> 4) * 17 + (o & 15);
        const float sv = sRed[0][idx] + sRed[1][idx] + sRed[2][idx] + sRed[3][idx];
        if (PACKED) dst[(size_t)pos * BK + o] = sv;        // ws[oij][bk]
        else        dst[(size_t)o * NPOS + pos] = sv;      // scattered fallback
    }
}

// ---- epilogue: ws[oij][bk] -> out[bk][oij] (proven round-3/4) ----
__global__ __launch_bounds__(256)
void transpose_out(const float* __restrict__ src, float* __restrict__ out) {
    __shared__ float tile[64][65];
    const int o0 = blockIdx.x * 64;
    const int k0 = blockIdx.y * 64;
    const int t  = threadIdx.x;
    const int tx = t & 63, ty = t >> 6;
    for (int r = ty; r < 64; r += 4) {
        const int oij = o0 + r;
        if (oij < NPOS) tile[r][tx] = src[(size_t)oij * BK + k0 + tx];
    }
    __syncthreads();
    for (int r = ty; r < 64; r += 4) {
        const int oij = o0 + tx;
        if (oij < NPOS) out[(size_t)(k0 + r) * NPOS + oij] = tile[tx][r];
    }
}

// ---- emergency fallback (ws too small): naive, correct, slow ----
__global__ __launch_bounds__(256)
void lc_naive(const float* __restrict__ x, const float* __restrict__ w,
              float* __restrict__ out) {
    const int gid = blockIdx.x * 256 + threadIdx.x;
    if (gid >= 32 * COUT * NPOS) return;
    const int j = gid % OUT_HW;
    int rest = gid / OUT_HW;
    const int i = rest % OUT_HW; rest /= OUT_HW;
    const int k = rest % COUT;
    const int b = rest / COUT;
    const float* wp = w + (size_t)(i * OUT_HW + j) * 6400 + k;
    float s = 0.f;
    for (int c = 0; c < CIN; ++c)
        for (int u = 0; u < 5; ++u)
            for (int v = 0; v < 5; ++v)
                s += x[((size_t)(b * CIN + c) * IN_HW + i + u) * IN_HW + j + v]
                   * wp[((c * 5 + u) * 5 + v) * COUT];
    out[gid] = s;
}

extern "C" void kernel_launch(void* const* d_in, const int* in_sizes, int n_in,
                              void* d_out, int out_size, void* d_ws, size_t ws_size,
                              hipStream_t stream) {
    const float* x = (const float*)d_in[0];
    const float* w = (const float*)d_in[1];
    float* out = (float*)d_out;

    const size_t xcBytes  = (size_t)XC_ELE * 2;        // 4,194,304
    const size_t outBytes = (size_t)NPOS * BK * 4;     // 7,372,800
    ushort* xc = (ushort*)d_ws;

    if (ws_size >= xcBytes + outBytes) {
        float* wsOut = (float*)((char*)d_ws + xcBytes);
        make_xc<<<32 * IN_HW, 256, 0, stream>>>(x, xc);
        lc_pos<1><<<NPOS, 256, 0, stream>>>(xc, w, wsOut);
        transpose_out<<<dim3((NPOS + 63) / 64, BK / 64), 256, 0, stream>>>(wsOut, out);
    } else if (ws_size >= xcBytes) {
        make_xc<<<32 * IN_HW, 256, 0, stream>>>(x, xc);
        lc_pos<0><<<NPOS, 256, 0, stream>>>(xc, w, out);
    } else {
        lc_naive<<<(32 * COUT * NPOS + 255) / 256, 256, 0, stream>>>(x, w, out);
    }
}

// Round 6
// 155.117 us; speedup vs baseline: 1.2254x; 1.2254x over previous
//
#include <hip/hip_runtime.h>
#include <hip/hip_bf16.h>

// Locally-connected conv, ALL FP32 in/out, bf16 MFMA compute.
//   x:   (32, 16, 64, 64)        float
//   w:   (60, 60, 16, 5, 5, 16)  float   (per-position 400x16, k innermost)
//   out: (32, 16, 60, 60)        float
//
// Round-6: fix round-5's scratch-spill (WRITE_SIZE 97 MB == W round-tripped
// through scratch).
//  * W staged via __builtin_amdgcn_global_load_lds width=16: 25 wave-ops x
//    1024B per position, raw [m][k] LDS layout (DMA needs contiguous
//    wave-uniform-base + lane*16). No VGPR/scratch round trip.
//  * A-fragments prefetched to registers BEFORE the barrier -> X's L2
//    gathers overlap the W DMA.
//  * [k][m] transpose on LDS read side: 8x ds_read_b32 per B-frag (4-way
//    bank conflicts ~ 1.58x on a minor term), cvt to bf16 in-reg.
//  * LDS 34.3 KB -> 4 blocks/CU.

#define OUT_HW 60
#define IN_HW  64
#define CIN    16
#define COUT   16
#define NPOS   3600              // OUT_HW*OUT_HW
#define BK     512               // NB*COUT
#define XC_ELE (32u * 64u * 64u * 16u)   // 2,097,152 bf16 elements

typedef __attribute__((ext_vector_type(8))) short bf16x8;
typedef __attribute__((ext_vector_type(4))) float f32x4;

static __device__ __forceinline__ unsigned pk2(float a, float b) {
    union { __hip_bfloat162 h; unsigned u; } cv;
    cv.h = __float22bfloat162_rn(make_float2(a, b));
    return cv.u;
}

// async global->LDS, 16B per lane; l must be wave-uniform, g per-lane.
static __device__ __forceinline__ void g2lds16(const float* g, float* l) {
    __builtin_amdgcn_global_load_lds(
        (const __attribute__((address_space(1))) unsigned int*)g,
        (__attribute__((address_space(3))) unsigned int*)l, 16, 0, 0);
}

// ---- prepass: xc[b][h][w][c] bf16 <- x[b][c][h][w] fp32 (proven r5) ----
__global__ __launch_bounds__(256)
void make_xc(const float* __restrict__ x, ushort* __restrict__ xc) {
    const int bh = blockIdx.x;               // b*64 + h
    const int b = bh >> 6, h = bh & 63;
    const int t = threadIdx.x;
    const int cq = t & 3, wc = t >> 2;
    const float* src = x + ((size_t)(b * CIN) * IN_HW + h) * IN_HW + wc;
    float f[4];
#pragma unroll
    for (int e = 0; e < 4; ++e)
        f[e] = src[(size_t)(cq * 4 + e) * (IN_HW * IN_HW)];
    union { ushort4 v; unsigned u[2]; } o;
    o.u[0] = pk2(f[0], f[1]);
    o.u[1] = pk2(f[2], f[3]);
    *(ushort4*)&xc[((size_t)bh * IN_HW + wc) * CIN + cq * 4] = o.v;
}

// ---- main: one block (256 thr, 4 K-split waves) per output position ----
template<int PACKED>
__global__ __launch_bounds__(256, 4)
void lc_pos(const ushort* __restrict__ xc, const float* __restrict__ w,
            float* __restrict__ dst) {
    __shared__ float sWraw[6400] __attribute__((aligned(16)));  // raw [m][k], 25,600 B
    __shared__ float sRed[4][32 * 17];                          //  8,704 B

    const int bid = blockIdx.x;
    const int pos = (bid & 7) * 450 + (bid >> 3);   // XCD swizzle (bijective)
    const int i = pos / OUT_HW, j = pos - i * OUT_HW;
    const int t = threadIdx.x;
    const int lane = t & 63, wv = t >> 6;
    const int l15 = lane & 15, q = lane >> 4;
    const int qh = q >> 1, c0 = (q & 1) << 3;

    // ---- W: async DMA, 25 x (64 lanes x 16B) = 25,600 B, raw load order ----
    const float* wsrc = w + (size_t)pos * 6400 + lane * 4;
    for (int o = wv; o < 25; o += 4)
        g2lds16(wsrc + o * 256, &sWraw[o * 256]);

    // ---- X: prefetch A-fragments to registers (overlaps the W DMA) ----
    const int base_hw = i * IN_HW + j;
    bf16x8 xa0[4], xa1[4];
#pragma unroll
    for (int it = 0; it < 4; ++it) {
        const int cc = wv + it * 4;
        if (cc < 13) {
            const int uvB = cc * 2 + qh;
            const int uvA = (uvB < 25) ? uvB : 24;   // clamped; W=0 there
            const int uA = (uvA * 13) >> 6;          // uv/5 for uv<=24
            const int vA = uvA - 5 * uA;
            const size_t xoff = (size_t)l15 * (IN_HW * IN_HW * CIN)
                              + (size_t)(base_hw + uA * IN_HW + vA) * CIN + c0;
            xa0[it] = *(const bf16x8*)(xc + xoff);                           // b = l15
            xa1[it] = *(const bf16x8*)(xc + xoff + 16u * IN_HW * IN_HW * CIN); // b+16
        }
    }

    __syncthreads();   // drains DMA + prefetch (vmcnt), then barrier

    // ---- MFMA: k_r=(uv,c), c innermost; wave wv does chunks {wv, wv+4, ...} ----
    f32x4 acc0 = {0.f, 0.f, 0.f, 0.f}, acc1 = {0.f, 0.f, 0.f, 0.f};
#pragma unroll
    for (int it = 0; it < 4; ++it) {
        const int cc = wv + it * 4;
        if (cc < 13) {
            const int uvB = cc * 2 + qh;
            const int okB = (uvB < 25);
            float bfv[8];
#pragma unroll
            for (int jj = 0; jj < 8; ++jj)      // m = (c0+jj)*25 + uvB, k = l15
                bfv[jj] = okB ? sWraw[(c0 + jj) * 400 + uvB * 16 + l15] : 0.f;
            union { bf16x8 v; unsigned u[4]; } pb;
#pragma unroll
            for (int jj = 0; jj < 4; ++jj) pb.u[jj] = pk2(bfv[2 * jj], bfv[2 * jj + 1]);
            acc0 = __builtin_amdgcn_mfma_f32_16x16x32_bf16(xa0[it], pb.v, acc0, 0, 0, 0);
            acc1 = __builtin_amdgcn_mfma_f32_16x16x32_bf16(xa1[it], pb.v, acc1, 0, 0, 0);
        }
    }

    // ---- K-split reduce (proven r4/r5 pattern) ----
#pragma unroll
    for (int r = 0; r < 4; ++r) {
        sRed[wv][(q * 4 + r) * 17 + l15]      = acc0[r];   // D rows b = q*4+r
        sRed[wv][(q * 4 + r + 16) * 17 + l15] = acc1[r];   // b + 16
    }
    __syncthreads();
#pragma unroll
    for (int h = 0; h < 2; ++h) {
        const int o = t + h * 256;                  // o = b*16 + k
        const int idx = (o >> 4) * 17 + (o & 15);
        const float sv = sRed[0][idx] + sRed[1][idx] + sRed[2][idx] + sRed[3][idx];
        if (PACKED) dst[(size_t)pos * BK + o] = sv;        // ws[oij][bk]
        else        dst[(size_t)o * NPOS + pos] = sv;      // scattered fallback
    }
}

// ---- epilogue: ws[oij][bk] -> out[bk][oij] (proven r3/r4/r5) ----
__global__ __launch_bounds__(256)
void transpose_out(const float* __restrict__ src, float* __restrict__ out) {
    __shared__ float tile[64][65];
    const int o0 = blockIdx.x * 64;
    const int k0 = blockIdx.y * 64;
    const int t  = threadIdx.x;
    const int tx = t & 63, ty = t >> 6;
    for (int r = ty; r < 64; r += 4) {
        const int oij = o0 + r;
        if (oij < NPOS) tile[r][tx] = src[(size_t)oij * BK + k0 + tx];
    }
    __syncthreads();
    for (int r = ty; r < 64; r += 4) {
        const int oij = o0 + tx;
        if (oij < NPOS) out[(size_t)(k0 + r) * NPOS + oij] = tile[tx][r];
    }
}

// ---- emergency fallback (ws too small): naive, correct, slow ----
__global__ __launch_bounds__(256)
void lc_naive(const float* __restrict__ x, const float* __restrict__ w,
              float* __restrict__ out) {
    const int gid = blockIdx.x * 256 + threadIdx.x;
    if (gid >= 32 * COUT * NPOS) return;
    const int j = gid % OUT_HW;
    int rest = gid / OUT_HW;
    const int i = rest % OUT_HW; rest /= OUT_HW;
    const int k = rest % COUT;
    const int b = rest / COUT;
    const float* wp = w + (size_t)(i * OUT_HW + j) * 6400 + k;
    float s = 0.f;
    for (int c = 0; c < CIN; ++c)
        for (int u = 0; u < 5; ++u)
            for (int v = 0; v < 5; ++v)
                s += x[((size_t)(b * CIN + c) * IN_HW + i + u) * IN_HW + j + v]
                   * wp[((c * 5 + u) * 5 + v) * COUT];
    out[gid] = s;
}

extern "C" void kernel_launch(void* const* d_in, const int* in_sizes, int n_in,
                              void* d_out, int out_size, void* d_ws, size_t ws_size,
                              hipStream_t stream) {
    const float* x = (const float*)d_in[0];
    const float* w = (const float*)d_in[1];
    float* out = (float*)d_out;

    const size_t xcBytes  = (size_t)XC_ELE * 2;        // 4,194,304
    const size_t outBytes = (size_t)NPOS * BK * 4;     // 7,372,800
    ushort* xc = (ushort*)d_ws;

    if (ws_size >= xcBytes + outBytes) {
        float* wsOut = (float*)((char*)d_ws + xcBytes);
        make_xc<<<32 * IN_HW, 256, 0, stream>>>(x, xc);
        lc_pos<1><<<NPOS, 256, 0, stream>>>(xc, w, wsOut);
        transpose_out<<<dim3((NPOS + 63) / 64, BK / 64), 256, 0, stream>>>(wsOut, out);
    } else if (ws_size >= xcBytes) {
        make_xc<<<32 * IN_HW, 256, 0, stream>>>(x, xc);
        lc_pos<0><<<NPOS, 256, 0, stream>>>(xc, w, out);
    } else {
        lc_naive<<<(32 * COUT * NPOS + 255) / 256, 256, 0, stream>>>(x, w, out);
    }
}